// Round 9
// baseline (241.020 us; speedup 1.0000x reference)
//
#include <hip/hip_runtime.h>
#include <stdint.h>

#define F8MAX 448.0f
#define QEPS 1e-12f
#define SCL_ONE 0x7F7F7F7F   // E8M0 exponent 127 => 2^0 = 1.0 per byte
#define AXB 4096             // amax partial blocks

typedef float floatx16 __attribute__((ext_vector_type(16)));
typedef int   intx4    __attribute__((ext_vector_type(4)));
typedef int   intx8    __attribute__((ext_vector_type(8)));

// ---------------- pass 1: dual per-block amax partials (x and w in one kernel) ----------------
__global__ __launch_bounds__(256) void amax_partial_xw(
    const float* __restrict__ x, int nx4,
    const float* __restrict__ w, int nw4,
    float* __restrict__ px, float* __restrict__ pw)
{
    const float4* x4 = (const float4*)x;
    const float4* w4 = (const float4*)w;
    int tid = blockIdx.x * 256 + threadIdx.x;
    int stride = gridDim.x * 256;
    float mx = 0.f, mw = 0.f;
    for (int i = tid; i < nx4; i += stride) {
        float4 v = x4[i];
        mx = fmaxf(mx, fmaxf(fmaxf(fabsf(v.x), fabsf(v.y)), fmaxf(fabsf(v.z), fabsf(v.w))));
    }
    for (int i = tid; i < nw4; i += stride) {
        float4 v = w4[i];
        mw = fmaxf(mw, fmaxf(fmaxf(fabsf(v.x), fabsf(v.y)), fmaxf(fabsf(v.z), fabsf(v.w))));
    }
    #pragma unroll
    for (int off = 32; off > 0; off >>= 1) {
        mx = fmaxf(mx, __shfl_xor(mx, off, 64));
        mw = fmaxf(mw, __shfl_xor(mw, off, 64));
    }
    __shared__ float smx[4], smw[4];
    if ((threadIdx.x & 63) == 0) { smx[threadIdx.x >> 6] = mx; smw[threadIdx.x >> 6] = mw; }
    __syncthreads();
    if (threadIdx.x == 0) {
        px[blockIdx.x] = fmaxf(fmaxf(smx[0], smx[1]), fmaxf(smx[2], smx[3]));
        pw[blockIdx.x] = fmaxf(fmaxf(smw[0], smw[1]), fmaxf(smw[2], smw[3]));
    }
}

// ---------------- pass 2: coalesced LDS-transposing quant into MX-scrambled layout -------------
// (unchanged from round 8 — round-8 null showed quant is not the critical phase; keep the
//  coalesced version, it is no worse and structurally cleaner)
__global__ __launch_bounds__(256) void quant_fused(
    const float* __restrict__ x, const float* __restrict__ w,
    uint8_t* __restrict__ x8, uint8_t* __restrict__ w8,
    const float* __restrict__ px, const float* __restrict__ pw,
    unsigned* __restrict__ hdr, int nhx, int nkt, int K)
{
    __shared__ uint8_t lds[65536];

    int bid = blockIdx.x;
    bool isw = (bid < 16);                 // w: 16 half-panels (N=1024)
    const float* par = isw ? pw : px;

    float m = 0.f;
    for (int i = threadIdx.x; i < AXB; i += 256) m = fmaxf(m, par[i]);
    #pragma unroll
    for (int off = 32; off > 0; off >>= 1) m = fmaxf(m, __shfl_xor(m, off, 64));
    __shared__ float red[4];
    if ((threadIdx.x & 63) == 0) red[threadIdx.x >> 6] = m;
    __syncthreads();
    float amax = fmaxf(fmaxf(red[0], red[1]), fmaxf(red[2], red[3]));

    float scale = fmaxf(amax, QEPS) / F8MAX;   // exactly the reference's scale
    float rs = 1.0f / scale;                   // reciprocal-multiply

    if (threadIdx.x == 0) {
        if (bid == 0)  hdr[1] = __float_as_uint(amax);   // amax_w for gemm epilogue
        if (bid == 16) hdr[0] = __float_as_uint(amax);   // amax_x
    }

    int hp = isw ? bid : (nhx - 1 - (bid - 16));   // x back-to-front: L3 reuse after amax
    const float* src = isw ? w : x;
    uint8_t* dst8 = isw ? w8 : x8;
    int p = hp >> 1, half = hp & 1;

    int wave = threadIdx.x >> 6, lane = threadIdx.x & 63;
    int K4 = K >> 2;

    // ---- phase A: rows -> LDS ----
    const float4* s4 = (const float4*)src + (size_t)(p * 128 + half * 64) * K4;
    uint32_t key = (lane >> 2) & 7;
    uint32_t lbase = ((uint32_t)(lane >> 4) * 4096) + (((lane >> 2) & 3) * 1024) + ((lane & 3) * 4);
    for (int rr = 0; rr < 16; rr++) {
        int r = rr * 4 + wave;
        const float4* rowp = s4 + (size_t)r * K4;
        #pragma unroll
        for (int j = 0; j < 4; j++) {
            float4 f = rowp[j * 64 + lane];    // 1KB contiguous per wave-instr
            int wd = 0;
            wd = __builtin_amdgcn_cvt_pk_fp8_f32(f.x * rs, f.y * rs, wd, false);
            wd = __builtin_amdgcn_cvt_pk_fp8_f32(f.z * rs, f.w * rs, wd, true);
            uint32_t a = (uint32_t)j * 16384 + lbase + (uint32_t)r * 16;
            a ^= (key << 4);
            *(int*)(lds + a) = wd;
        }
    }
    __syncthreads();

    // ---- phase B: LDS -> global, 64 x 1KB chunks, wave-contiguous ----
    uint8_t* outb = dst8 + (size_t)(p * nkt) * 8192 + half * 1024;
    for (int i = 0; i < 16; i++) {
        int c = i * 4 + wave;                  // chunk 0..63
        int kt = c >> 2, hpc = c & 3;
        uint32_t k2 = (uint32_t)(((kt & 1) << 2) | hpc);
        uint32_t a = (uint32_t)c * 1024 + (((uint32_t)lane * 16) ^ (k2 << 4));
        int4 v = *(const int4*)(lds + a);
        *(int4*)(outb + (size_t)kt * 8192 + hpc * 2048 + lane * 16) = v;
    }
}

// ---------------- pass 3: MX-scaled fp8 GEMM, 256x128 tile, 2 blocks/CU ----------------
// C[M,N] = (A8 . B8^T)*s + bias; 4 waves (2M x 2N), per-wave 128x64 out, BK=64,
// 2 LDS buffers (48KB) -> 2 blocks/CU so one block's epilogue/drains overlap the
// other's MFMA (fix for 1-block/CU epilogue serialization diagnosed in round 8).
__global__ __launch_bounds__(256, 2) void gemm_fp8_mx(
    const uint8_t* __restrict__ A8, const uint8_t* __restrict__ B8,
    float* __restrict__ C, const float* __restrict__ bias,
    const unsigned* __restrict__ hdr, int N, int nkt, int nbn)
{
    __shared__ uint8_t ls[2 * 24576];   // buffer b: A at +0 (16KB), B at +16384 (8KB)

    // XCD-chunked bijective swizzle (grid % 8 == 0)
    int nwg = gridDim.x;
    int bid = blockIdx.x;
    if ((nwg & 7) == 0) {
        int chunk = nwg >> 3;
        bid = (blockIdx.x & 7) * chunk + (blockIdx.x >> 3);
    }
    int bm = bid / nbn, bn = bid - bm * nbn;

    int t = threadIdx.x;
    int wave = t >> 6, lane = t & 63;
    int wr = wave >> 1, wc = wave & 1;        // 2(M) x 2(N)
    int hl = lane >> 5, l31 = lane & 31;

    // ---- staging: 24 x 1KB chunks per K-tile (A: 0..15, B: 16..23); wave v owns v*6+p ----
    const uint8_t* gs[6];
    uint32_t lo[6];
    #pragma unroll
    for (int p = 0; p < 6; p++) {
        int c = wave * 6 + p;
        if (c < 16) {
            int h = c >> 3, sub = c & 7;
            gs[p] = A8 + (size_t)(bm * 2 + h) * nkt * 8192 + sub * 1024 + lane * 16;
        } else {
            int sub = c - 16;
            gs[p] = B8 + (size_t)bn * nkt * 8192 + sub * 1024 + lane * 16;
        }
        lo[p] = (uint32_t)c * 1024;
    }

#define ISSUE(P, KT2, B2)                                                        \
    __builtin_amdgcn_global_load_lds(                                            \
        (const __attribute__((address_space(1))) void*)(gs[P] + (size_t)(KT2) * 8192), \
        (__attribute__((address_space(3))) void*)(ls + (B2) * 24576 + lo[P]),    \
        16, 0, 0)

    // fragment read bases (A rows wr*128 + m*32 + l31; B rows wc*64 + n*32 + l31)
    const uint8_t* baseA = ls + wr * 8192 + hl * 4096 + l31 * 16;
    const uint8_t* baseB = ls + 16384 + hl * 4096 + wc * 1024 + l31 * 16;

    floatx16 acc[4][2];
    #pragma unroll
    for (int m = 0; m < 4; m++)
        #pragma unroll
        for (int n = 0; n < 2; n++)
            acc[m][n] = (floatx16)(0.0f);

#define RD8(BASE, OFF) __builtin_shufflevector(                         \
        *(const intx4*)((BASE) + (OFF)),                                \
        *(const intx4*)((BASE) + (OFF) + 2048), 0, 1, 2, 3, 4, 5, 6, 7)

#define MMX(m, n) acc[m][n] = __builtin_amdgcn_mfma_scale_f32_32x32x64_f8f6f4( \
        af[m], bf[n], acc[m][n], 0, 0, 0, SCL_ONE, 0, SCL_ONE)

    // ---- prologue: stage tile 0 ----
    #pragma unroll
    for (int p = 0; p < 6; p++) ISSUE(p, 0, 0);
    asm volatile("s_waitcnt vmcnt(0)" ::: "memory");
    asm volatile("s_barrier" ::: "memory");

    int buf = 0;
    for (int kt = 0; kt < nkt; kt++) {
        bool pf = (kt + 1 < nkt);
        if (pf) {
            #pragma unroll
            for (int p = 0; p < 6; p++) ISSUE(p, kt + 1, buf ^ 1);
        }
        const uint8_t* cA = baseA + buf * 24576;
        const uint8_t* cB = baseB + buf * 24576;
        intx8 af[4], bf[2];

        af[0] = RD8(cA, 0);    af[1] = RD8(cA, 512);
        bf[0] = RD8(cB, 0);    bf[1] = RD8(cB, 512);
        af[2] = RD8(cA, 1024); af[3] = RD8(cA, 1536);

        __builtin_amdgcn_s_setprio(1);
        MMX(0, 0); MMX(0, 1); MMX(1, 0); MMX(1, 1);
        MMX(2, 0); MMX(2, 1); MMX(3, 0); MMX(3, 1);
        __builtin_amdgcn_s_setprio(0);

        if (pf) {
            asm volatile("s_waitcnt vmcnt(0)" ::: "memory");   // prefetch landed
            asm volatile("s_barrier" ::: "memory");            // all waves: buf^1 ready, buf free
        }
        buf ^= 1;
    }

    float sxv = fmaxf(__uint_as_float(hdr[0]), QEPS) / F8MAX;
    float swv = fmaxf(__uint_as_float(hdr[1]), QEPS) / F8MAX;
    float s = sxv * swv;

    // C/D 32x32: col = lane&31, row = (reg&3) + 8*(reg>>2) + 4*(lane>>5)
    #pragma unroll
    for (int m = 0; m < 4; m++) {
        int row0 = bm * 256 + wr * 128 + m * 32 + 4 * hl;
        #pragma unroll
        for (int n = 0; n < 2; n++) {
            int col = bn * 128 + wc * 64 + n * 32 + l31;
            float bv = bias[col];
            #pragma unroll
            for (int reg = 0; reg < 16; reg++) {
                int row = row0 + (reg & 3) + 8 * (reg >> 2);
                __builtin_nontemporal_store(acc[m][n][reg] * s + bv, &C[(size_t)row * N + col]);
            }
        }
    }
#undef ISSUE
#undef RD8
#undef MMX
}

extern "C" void kernel_launch(void* const* d_in, const int* in_sizes, int n_in,
                              void* d_out, int out_size, void* d_ws, size_t ws_size,
                              hipStream_t stream)
{
    const float* x    = (const float*)d_in[0];
    const float* w    = (const float*)d_in[1];
    const float* bias = (const float*)d_in[2];
    float* out = (float*)d_out;

    int N = in_sizes[2];                 // 1024
    int K = in_sizes[1] / N;             // 1024
    int M = in_sizes[0] / K;             // 65536
    int nx = in_sizes[0];
    int nw = in_sizes[1];
    int nkt = K / 64;                    // 16

    uint8_t* ws = (uint8_t*)d_ws;
    unsigned* hdr = (unsigned*)ws;                    // [0]=amax_x bits, [1]=amax_w bits
    float* px = (float*)(ws + 64);                    // 4096 partials (x)
    float* pw = (float*)(ws + 64 + 16384);            // 4096 partials (w)
    uint8_t* w8 = ws + 65536;
    uint8_t* x8 = ws + 65536 + (size_t)N * K;

    int nhx = (M / 128) * 2;             // 1024 half-panels of x
    int nhw = (N / 128) * 2;             // 16 half-panels of w

    amax_partial_xw<<<AXB, 256, 0, stream>>>(x, nx / 4, w, nw / 4, px, pw);
    quant_fused<<<nhw + nhx, 256, 0, stream>>>(x, w, x8, w8, px, pw, hdr, nhx, nkt, K);

    int nbm = M / 256, nbn = N / 128;    // 256 x 8 = 2048 blocks
    gemm_fp8_mx<<<nbm * nbn, 256, 0, stream>>>(x8, w8, out, bias, hdr, N, nkt, nbn);
}

// Round 10
// 230.701 us; speedup vs baseline: 1.0447x; 1.0447x over previous
//
#include <hip/hip_runtime.h>
#include <stdint.h>

#define F8MAX 448.0f
#define QEPS 1e-12f
#define SCL_ONE 0x7F7F7F7F   // E8M0 exponent 127 => 2^0 = 1.0 per byte
#define AXB 4096             // amax partial blocks

typedef float floatx16 __attribute__((ext_vector_type(16)));
typedef int   intx4    __attribute__((ext_vector_type(4)));
typedef int   intx8    __attribute__((ext_vector_type(8)));

// ---------------- pass 1: dual per-block amax partials (x and w in one kernel) ----------------
__global__ __launch_bounds__(256) void amax_partial_xw(
    const float* __restrict__ x, int nx4,
    const float* __restrict__ w, int nw4,
    float* __restrict__ px, float* __restrict__ pw)
{
    const float4* x4 = (const float4*)x;
    const float4* w4 = (const float4*)w;
    int tid = blockIdx.x * 256 + threadIdx.x;
    int stride = gridDim.x * 256;
    float mx = 0.f, mw = 0.f;
    for (int i = tid; i < nx4; i += stride) {
        float4 v = x4[i];
        mx = fmaxf(mx, fmaxf(fmaxf(fabsf(v.x), fabsf(v.y)), fmaxf(fabsf(v.z), fabsf(v.w))));
    }
    for (int i = tid; i < nw4; i += stride) {
        float4 v = w4[i];
        mw = fmaxf(mw, fmaxf(fmaxf(fabsf(v.x), fabsf(v.y)), fmaxf(fabsf(v.z), fabsf(v.w))));
    }
    #pragma unroll
    for (int off = 32; off > 0; off >>= 1) {
        mx = fmaxf(mx, __shfl_xor(mx, off, 64));
        mw = fmaxf(mw, __shfl_xor(mw, off, 64));
    }
    __shared__ float smx[4], smw[4];
    if ((threadIdx.x & 63) == 0) { smx[threadIdx.x >> 6] = mx; smw[threadIdx.x >> 6] = mw; }
    __syncthreads();
    if (threadIdx.x == 0) {
        px[blockIdx.x] = fmaxf(fmaxf(smx[0], smx[1]), fmaxf(smx[2], smx[3]));
        pw[blockIdx.x] = fmaxf(fmaxf(smw[0], smw[1]), fmaxf(smw[2], smw[3]));
    }
}

// ---------------- pass 2: coalesced LDS-transposing quant into MX-scrambled layout -------------
// (byte-identical to round 8 — known good)
__global__ __launch_bounds__(256) void quant_fused(
    const float* __restrict__ x, const float* __restrict__ w,
    uint8_t* __restrict__ x8, uint8_t* __restrict__ w8,
    const float* __restrict__ px, const float* __restrict__ pw,
    unsigned* __restrict__ hdr, int nhx, int nkt, int K)
{
    __shared__ uint8_t lds[65536];

    int bid = blockIdx.x;
    bool isw = (bid < 16);                 // w: 16 half-panels (N=1024)
    const float* par = isw ? pw : px;

    float m = 0.f;
    for (int i = threadIdx.x; i < AXB; i += 256) m = fmaxf(m, par[i]);
    #pragma unroll
    for (int off = 32; off > 0; off >>= 1) m = fmaxf(m, __shfl_xor(m, off, 64));
    __shared__ float red[4];
    if ((threadIdx.x & 63) == 0) red[threadIdx.x >> 6] = m;
    __syncthreads();
    float amax = fmaxf(fmaxf(red[0], red[1]), fmaxf(red[2], red[3]));

    float scale = fmaxf(amax, QEPS) / F8MAX;   // exactly the reference's scale
    float rs = 1.0f / scale;                   // reciprocal-multiply

    if (threadIdx.x == 0) {
        if (bid == 0)  hdr[1] = __float_as_uint(amax);   // amax_w for gemm epilogue
        if (bid == 16) hdr[0] = __float_as_uint(amax);   // amax_x
    }

    int hp = isw ? bid : (nhx - 1 - (bid - 16));   // x back-to-front: L3 reuse after amax
    const float* src = isw ? w : x;
    uint8_t* dst8 = isw ? w8 : x8;
    int p = hp >> 1, half = hp & 1;

    int wave = threadIdx.x >> 6, lane = threadIdx.x & 63;
    int K4 = K >> 2;

    // ---- phase A: rows -> LDS ----
    const float4* s4 = (const float4*)src + (size_t)(p * 128 + half * 64) * K4;
    uint32_t key = (lane >> 2) & 7;
    uint32_t lbase = ((uint32_t)(lane >> 4) * 4096) + (((lane >> 2) & 3) * 1024) + ((lane & 3) * 4);
    for (int rr = 0; rr < 16; rr++) {
        int r = rr * 4 + wave;
        const float4* rowp = s4 + (size_t)r * K4;
        #pragma unroll
        for (int j = 0; j < 4; j++) {
            float4 f = rowp[j * 64 + lane];    // 1KB contiguous per wave-instr
            int wd = 0;
            wd = __builtin_amdgcn_cvt_pk_fp8_f32(f.x * rs, f.y * rs, wd, false);
            wd = __builtin_amdgcn_cvt_pk_fp8_f32(f.z * rs, f.w * rs, wd, true);
            uint32_t a = (uint32_t)j * 16384 + lbase + (uint32_t)r * 16;
            a ^= (key << 4);
            *(int*)(lds + a) = wd;
        }
    }
    __syncthreads();

    // ---- phase B: LDS -> global, 64 x 1KB chunks, wave-contiguous ----
    uint8_t* outb = dst8 + (size_t)(p * nkt) * 8192 + half * 1024;
    for (int i = 0; i < 16; i++) {
        int c = i * 4 + wave;                  // chunk 0..63
        int kt = c >> 2, hpc = c & 3;
        uint32_t k2 = (uint32_t)(((kt & 1) << 2) | hpc);
        uint32_t a = (uint32_t)c * 1024 + (((uint32_t)lane * 16) ^ (k2 << 4));
        int4 v = *(const int4*)(lds + a);
        *(int4*)(outb + (size_t)kt * 8192 + hpc * 2048 + lane * 16) = v;
    }
}

// ---------------- pass 3: MX-scaled fp8 GEMM, 256x128 tile, 3-buffer counted-vmcnt, 2 blk/CU ---
// C[M,N] = (A8 . B8^T)*s + bias; 4 waves (2M x 2N), per-wave 128x64 out, BK=64.
// 3 LDS buffers (72KB) -> 2 blocks/CU (VGPR<=256): one block's epilogue (HBM writes)
// overlaps the other's LDS-bound K-loop; counted vmcnt(6) keeps prefetch 2 tiles deep
// (round-9 regression isolated to the lost counted-vmcnt pipeline, not the tile size).
__global__ __launch_bounds__(256, 2) void gemm_fp8_mx(
    const uint8_t* __restrict__ A8, const uint8_t* __restrict__ B8,
    float* __restrict__ C, const float* __restrict__ bias,
    const unsigned* __restrict__ hdr, int N, int nkt, int nbn)
{
    __shared__ uint8_t ls[3 * 24576];   // per buffer: A 16KB @ +0, B 8KB @ +16384

    // XCD-chunked bijective swizzle (grid % 8 == 0)
    int nwg = gridDim.x;
    int bid = blockIdx.x;
    if ((nwg & 7) == 0) {
        int chunk = nwg >> 3;
        bid = (blockIdx.x & 7) * chunk + (blockIdx.x >> 3);
    }
    int bm = bid / nbn, bn = bid - bm * nbn;

    int t = threadIdx.x;
    int wave = t >> 6, lane = t & 63;
    int wr = wave >> 1, wc = wave & 1;        // 2(M) x 2(N)
    int hl = lane >> 5, l31 = lane & 31;

    // ---- staging: 24 x 1KB chunks per K-tile (A: 0..15, B: 16..23); wave v owns v*6+p ----
    const uint8_t* gs[6];
    uint32_t lo[6];
    #pragma unroll
    for (int p = 0; p < 6; p++) {
        int c = wave * 6 + p;
        if (c < 16) {
            int h = c >> 3, sub = c & 7;
            gs[p] = A8 + (size_t)(bm * 2 + h) * nkt * 8192 + sub * 1024 + lane * 16;
        } else {
            int sub = c - 16;
            gs[p] = B8 + (size_t)bn * nkt * 8192 + sub * 1024 + lane * 16;
        }
        lo[p] = (uint32_t)c * 1024;
    }

#define ISSUE(P, KT2, B2)                                                        \
    __builtin_amdgcn_global_load_lds(                                            \
        (const __attribute__((address_space(1))) void*)(gs[P] + (size_t)(KT2) * 8192), \
        (__attribute__((address_space(3))) void*)(ls + (B2) * 24576 + lo[P]),    \
        16, 0, 0)

    // fragment read bases (A rows wr*128 + m*32 + l31; B rows wc*64 + n*32 + l31)
    const uint8_t* baseA = ls + wr * 8192 + hl * 4096 + l31 * 16;
    const uint8_t* baseB = ls + 16384 + hl * 4096 + wc * 1024 + l31 * 16;

    floatx16 acc[4][2];
    #pragma unroll
    for (int m = 0; m < 4; m++)
        #pragma unroll
        for (int n = 0; n < 2; n++)
            acc[m][n] = (floatx16)(0.0f);

#define RD8(BASE, OFF) __builtin_shufflevector(                         \
        *(const intx4*)((BASE) + (OFF)),                                \
        *(const intx4*)((BASE) + (OFF) + 2048), 0, 1, 2, 3, 4, 5, 6, 7)

#define MMX(m, n) acc[m][n] = __builtin_amdgcn_mfma_scale_f32_32x32x64_f8f6f4( \
        af[m], bf[n], acc[m][n], 0, 0, 0, SCL_ONE, 0, SCL_ONE)

    // ---- prologue: stage tiles 0 and 1 ----
    #pragma unroll
    for (int p = 0; p < 6; p++) ISSUE(p, 0, 0);
    #pragma unroll
    for (int p = 0; p < 6; p++) ISSUE(p, 1, 1);
    asm volatile("s_waitcnt vmcnt(6)" ::: "memory");   // tile 0 landed; tile 1 in flight
    asm volatile("s_barrier" ::: "memory");

    int cur = 0;
    for (int kt = 0; kt < nkt; kt++) {
        bool pf = (kt + 2 < nkt);
        int ib = cur - 1; if (ib < 0) ib += 3;          // (kt+2) % 3
        const uint8_t* cA = baseA + cur * 24576;
        const uint8_t* cB = baseB + cur * 24576;
        intx8 af[4], bf[2];

        if (pf) {
            #pragma unroll
            for (int p = 0; p < 6; p++) ISSUE(p, kt + 2, ib);
        }

        af[0] = RD8(cA, 0);    af[1] = RD8(cA, 512);
        bf[0] = RD8(cB, 0);    bf[1] = RD8(cB, 512);
        af[2] = RD8(cA, 1024); af[3] = RD8(cA, 1536);

        __builtin_amdgcn_s_setprio(1);
        MMX(0, 0); MMX(0, 1); MMX(1, 0); MMX(1, 1);
        MMX(2, 0); MMX(2, 1); MMX(3, 0); MMX(3, 1);
        __builtin_amdgcn_s_setprio(0);

        if (kt + 1 < nkt) {
            if (pf) asm volatile("s_waitcnt vmcnt(6)" ::: "memory");  // kt+1 landed; kt+2 in flight
            else    asm volatile("s_waitcnt vmcnt(0)" ::: "memory");
            asm volatile("s_barrier" ::: "memory");
        }
        cur++; if (cur == 3) cur = 0;
    }

    float sxv = fmaxf(__uint_as_float(hdr[0]), QEPS) / F8MAX;
    float swv = fmaxf(__uint_as_float(hdr[1]), QEPS) / F8MAX;
    float s = sxv * swv;

    // C/D 32x32: col = lane&31, row = (reg&3) + 8*(reg>>2) + 4*(lane>>5)
    #pragma unroll
    for (int m = 0; m < 4; m++) {
        int row0 = bm * 256 + wr * 128 + m * 32 + 4 * hl;
        #pragma unroll
        for (int n = 0; n < 2; n++) {
            int col = bn * 128 + wc * 64 + n * 32 + l31;
            float bv = bias[col];
            #pragma unroll
            for (int reg = 0; reg < 16; reg++) {
                int row = row0 + (reg & 3) + 8 * (reg >> 2);
                __builtin_nontemporal_store(acc[m][n][reg] * s + bv, &C[(size_t)row * N + col]);
            }
        }
    }
#undef ISSUE
#undef RD8
#undef MMX
}

extern "C" void kernel_launch(void* const* d_in, const int* in_sizes, int n_in,
                              void* d_out, int out_size, void* d_ws, size_t ws_size,
                              hipStream_t stream)
{
    const float* x    = (const float*)d_in[0];
    const float* w    = (const float*)d_in[1];
    const float* bias = (const float*)d_in[2];
    float* out = (float*)d_out;

    int N = in_sizes[2];                 // 1024
    int K = in_sizes[1] / N;             // 1024
    int M = in_sizes[0] / K;             // 65536
    int nx = in_sizes[0];
    int nw = in_sizes[1];
    int nkt = K / 64;                    // 16

    uint8_t* ws = (uint8_t*)d_ws;
    unsigned* hdr = (unsigned*)ws;                    // [0]=amax_x bits, [1]=amax_w bits
    float* px = (float*)(ws + 64);                    // 4096 partials (x)
    float* pw = (float*)(ws + 64 + 16384);            // 4096 partials (w)
    uint8_t* w8 = ws + 65536;
    uint8_t* x8 = ws + 65536 + (size_t)N * K;

    int nhx = (M / 128) * 2;             // 1024 half-panels of x
    int nhw = (N / 128) * 2;             // 16 half-panels of w

    amax_partial_xw<<<AXB, 256, 0, stream>>>(x, nx / 4, w, nw / 4, px, pw);
    quant_fused<<<nhw + nhx, 256, 0, stream>>>(x, w, x8, w8, px, pw, hdr, nhx, nkt, K);

    int nbm = M / 256, nbn = N / 128;    // 256 x 8 = 2048 blocks
    gemm_fp8_mx<<<nbm * nbn, 256, 0, stream>>>(x8, w8, out, bias, hdr, N, nkt, nbn);
}

// Round 11
// 217.644 us; speedup vs baseline: 1.1074x; 1.0600x over previous
//
#include <hip/hip_runtime.h>
#include <stdint.h>

#define F8MAX 448.0f
#define QEPS 1e-12f
#define SCL_ONE 0x7F7F7F7F   // E8M0 exponent 127 => 2^0 = 1.0 per byte
#define AXB 4096             // amax partial blocks

typedef float floatx16 __attribute__((ext_vector_type(16)));
typedef int   intx4    __attribute__((ext_vector_type(4)));
typedef int   intx8    __attribute__((ext_vector_type(8)));

// ---------------- pass 1: dual per-block amax partials (x and w in one kernel) ----------------
__global__ __launch_bounds__(256) void amax_partial_xw(
    const float* __restrict__ x, int nx4,
    const float* __restrict__ w, int nw4,
    float* __restrict__ px, float* __restrict__ pw)
{
    const float4* x4 = (const float4*)x;
    const float4* w4 = (const float4*)w;
    int tid = blockIdx.x * 256 + threadIdx.x;
    int stride = gridDim.x * 256;
    float mx = 0.f, mw = 0.f;
    for (int i = tid; i < nx4; i += stride) {
        float4 v = x4[i];
        mx = fmaxf(mx, fmaxf(fmaxf(fabsf(v.x), fabsf(v.y)), fmaxf(fabsf(v.z), fabsf(v.w))));
    }
    for (int i = tid; i < nw4; i += stride) {
        float4 v = w4[i];
        mw = fmaxf(mw, fmaxf(fmaxf(fabsf(v.x), fabsf(v.y)), fmaxf(fabsf(v.z), fabsf(v.w))));
    }
    #pragma unroll
    for (int off = 32; off > 0; off >>= 1) {
        mx = fmaxf(mx, __shfl_xor(mx, off, 64));
        mw = fmaxf(mw, __shfl_xor(mw, off, 64));
    }
    __shared__ float smx[4], smw[4];
    if ((threadIdx.x & 63) == 0) { smx[threadIdx.x >> 6] = mx; smw[threadIdx.x >> 6] = mw; }
    __syncthreads();
    if (threadIdx.x == 0) {
        px[blockIdx.x] = fmaxf(fmaxf(smx[0], smx[1]), fmaxf(smx[2], smx[3]));
        pw[blockIdx.x] = fmaxf(fmaxf(smw[0], smw[1]), fmaxf(smw[2], smw[3]));
    }
}

// ---------------- pass 2: coalesced LDS-transposing quant into MX-scrambled layout -------------
// (byte-identical to round 8 — known good)
__global__ __launch_bounds__(256) void quant_fused(
    const float* __restrict__ x, const float* __restrict__ w,
    uint8_t* __restrict__ x8, uint8_t* __restrict__ w8,
    const float* __restrict__ px, const float* __restrict__ pw,
    unsigned* __restrict__ hdr, int nhx, int nkt, int K)
{
    __shared__ uint8_t lds[65536];

    int bid = blockIdx.x;
    bool isw = (bid < 16);                 // w: 16 half-panels (N=1024)
    const float* par = isw ? pw : px;

    float m = 0.f;
    for (int i = threadIdx.x; i < AXB; i += 256) m = fmaxf(m, par[i]);
    #pragma unroll
    for (int off = 32; off > 0; off >>= 1) m = fmaxf(m, __shfl_xor(m, off, 64));
    __shared__ float red[4];
    if ((threadIdx.x & 63) == 0) red[threadIdx.x >> 6] = m;
    __syncthreads();
    float amax = fmaxf(fmaxf(red[0], red[1]), fmaxf(red[2], red[3]));

    float scale = fmaxf(amax, QEPS) / F8MAX;   // exactly the reference's scale
    float rs = 1.0f / scale;                   // reciprocal-multiply

    if (threadIdx.x == 0) {
        if (bid == 0)  hdr[1] = __float_as_uint(amax);   // amax_w for gemm epilogue
        if (bid == 16) hdr[0] = __float_as_uint(amax);   // amax_x
    }

    int hp = isw ? bid : (nhx - 1 - (bid - 16));   // x back-to-front: L3 reuse after amax
    const float* src = isw ? w : x;
    uint8_t* dst8 = isw ? w8 : x8;
    int p = hp >> 1, half = hp & 1;

    int wave = threadIdx.x >> 6, lane = threadIdx.x & 63;
    int K4 = K >> 2;

    // ---- phase A: rows -> LDS ----
    const float4* s4 = (const float4*)src + (size_t)(p * 128 + half * 64) * K4;
    uint32_t key = (lane >> 2) & 7;
    uint32_t lbase = ((uint32_t)(lane >> 4) * 4096) + (((lane >> 2) & 3) * 1024) + ((lane & 3) * 4);
    for (int rr = 0; rr < 16; rr++) {
        int r = rr * 4 + wave;
        const float4* rowp = s4 + (size_t)r * K4;
        #pragma unroll
        for (int j = 0; j < 4; j++) {
            float4 f = rowp[j * 64 + lane];    // 1KB contiguous per wave-instr
            int wd = 0;
            wd = __builtin_amdgcn_cvt_pk_fp8_f32(f.x * rs, f.y * rs, wd, false);
            wd = __builtin_amdgcn_cvt_pk_fp8_f32(f.z * rs, f.w * rs, wd, true);
            uint32_t a = (uint32_t)j * 16384 + lbase + (uint32_t)r * 16;
            a ^= (key << 4);
            *(int*)(lds + a) = wd;
        }
    }
    __syncthreads();

    // ---- phase B: LDS -> global, 64 x 1KB chunks, wave-contiguous ----
    uint8_t* outb = dst8 + (size_t)(p * nkt) * 8192 + half * 1024;
    for (int i = 0; i < 16; i++) {
        int c = i * 4 + wave;                  // chunk 0..63
        int kt = c >> 2, hpc = c & 3;
        uint32_t k2 = (uint32_t)(((kt & 1) << 2) | hpc);
        uint32_t a = (uint32_t)c * 1024 + (((uint32_t)lane * 16) ^ (k2 << 4));
        int4 v = *(const int4*)(lds + a);
        *(int4*)(outb + (size_t)kt * 8192 + hpc * 2048 + lane * 16) = v;
    }
}

// ---------------- pass 3: MX-scaled fp8 GEMM, 256^2 tile, 4-buffer depth-3 pipeline ------------
// C[M,N] = (A8 . B8^T)*s + bias; 8 waves (2M x 4N), BK=64, 4 LDS buffers (128KB, 1 blk/CU),
// prefetch 3 tiles ahead, counted vmcnt(8) steady-state (T4): one extra buffer of slack
// absorbs L2-miss/L3-latency jitter on staging that a 2-deep pipeline exposes at the barrier.
__global__ __launch_bounds__(512, 1) void gemm_fp8_mx(
    const uint8_t* __restrict__ A8, const uint8_t* __restrict__ B8,
    float* __restrict__ C, const float* __restrict__ bias,
    const unsigned* __restrict__ hdr, int N, int nkt, int nbn)
{
    __shared__ uint8_t lsA[4 * 16384];
    __shared__ uint8_t lsB[4 * 16384];

    // XCD-chunked bijective swizzle (grid % 8 == 0): each XCD gets a contiguous bm range
    int nwg = gridDim.x;
    int bid = blockIdx.x;
    if ((nwg & 7) == 0) {
        int chunk = nwg >> 3;
        bid = (blockIdx.x & 7) * chunk + (blockIdx.x >> 3);
    }
    int bm = bid / nbn, bn = bid - bm * nbn;

    int t = threadIdx.x;
    int wave = t >> 6, lane = t & 63;
    int wr = wave >> 2, wc = wave & 3;        // 2(M) x 4(N)
    int hl = lane >> 5, l31 = lane & 31;

    // ---- staging chunk map: 32 x 1KB chunks per K-tile; wave v owns chunks v*4+p ----
    const uint8_t* gsrc0; const uint8_t* gsrc1; const uint8_t* gsrc2; const uint8_t* gsrc3;
    uint32_t ld0, ld1, ld2, ld3;
    bool isA = (wave < 4);
    {
        int c0 = wave * 4;
        #pragma unroll
        for (int p = 0; p < 4; p++) {
            int c = c0 + p;
            const uint8_t* g;
            uint32_t l;
            if (c < 16) {
                int h = c >> 3, sub = c & 7;
                g = A8 + (size_t)(bm * 2 + h) * nkt * 8192 + sub * 1024 + lane * 16;
                l = (uint32_t)c * 1024;
            } else {
                int cc = c - 16, h = cc >> 3, sub = cc & 7;
                g = B8 + (size_t)(bn * 2 + h) * nkt * 8192 + sub * 1024 + lane * 16;
                l = (uint32_t)cc * 1024;
            }
            if (p == 0) { gsrc0 = g; ld0 = l; }
            else if (p == 1) { gsrc1 = g; ld1 = l; }
            else if (p == 2) { gsrc2 = g; ld2 = l; }
            else { gsrc3 = g; ld3 = l; }
        }
    }
    uint8_t* lsbase = isA ? lsA : lsB;

#define ISSUE(GP, LO, KT2, B2)                                                   \
    __builtin_amdgcn_global_load_lds(                                            \
        (const __attribute__((address_space(1))) void*)((GP) + (size_t)(KT2) * 8192), \
        (__attribute__((address_space(3))) void*)(lsbase + (B2) * 16384 + (LO)), \
        16, 0, 0)

    // fragment read bases
    const uint8_t* baseA = lsA + wr * 8192 + hl * 4096 + l31 * 16;
    const uint8_t* baseB = lsB + (wc >> 1) * 8192 + hl * 4096 + (wc & 1) * 1024 + l31 * 16;

    floatx16 acc[4][2];
    #pragma unroll
    for (int m = 0; m < 4; m++)
        #pragma unroll
        for (int n = 0; n < 2; n++)
            acc[m][n] = (floatx16)(0.0f);

#define RD8(BASE, OFF) __builtin_shufflevector(                         \
        *(const intx4*)((BASE) + (OFF)),                                \
        *(const intx4*)((BASE) + (OFF) + 2048), 0, 1, 2, 3, 4, 5, 6, 7)

#define MMX(m, n) acc[m][n] = __builtin_amdgcn_mfma_scale_f32_32x32x64_f8f6f4( \
        af[m], bf[n], acc[m][n], 0, 0, 0, SCL_ONE, 0, SCL_ONE)

    // ---- prologue: stage tiles 0, 1, 2 ----
    ISSUE(gsrc0, ld0, 0, 0); ISSUE(gsrc1, ld1, 0, 0); ISSUE(gsrc2, ld2, 0, 0); ISSUE(gsrc3, ld3, 0, 0);
    ISSUE(gsrc0, ld0, 1, 1); ISSUE(gsrc1, ld1, 1, 1); ISSUE(gsrc2, ld2, 1, 1); ISSUE(gsrc3, ld3, 1, 1);
    ISSUE(gsrc0, ld0, 2, 2); ISSUE(gsrc1, ld1, 2, 2); ISSUE(gsrc2, ld2, 2, 2); ISSUE(gsrc3, ld3, 2, 2);
    asm volatile("s_waitcnt vmcnt(8)" ::: "memory");   // tile 0 landed; 1,2 in flight
    asm volatile("s_barrier" ::: "memory");

    for (int kt = 0; kt < nkt; kt++) {
        int cur = kt & 3;
        int ib = (cur + 3) & 3;                         // (kt+3) % 4
        const uint8_t* cA = baseA + cur * 16384;
        const uint8_t* cB = baseB + cur * 16384;
        intx8 af[4], bf[2];

        if (kt + 3 < nkt) {
            ISSUE(gsrc0, ld0, kt + 3, ib); ISSUE(gsrc1, ld1, kt + 3, ib);
            ISSUE(gsrc2, ld2, kt + 3, ib); ISSUE(gsrc3, ld3, kt + 3, ib);
        }

        af[0] = RD8(cA, 0);    af[1] = RD8(cA, 512);
        bf[0] = RD8(cB, 0);    bf[1] = RD8(cB, 512);
        af[2] = RD8(cA, 1024); af[3] = RD8(cA, 1536);

        __builtin_amdgcn_s_setprio(1);
        MMX(0, 0); MMX(0, 1); MMX(1, 0); MMX(1, 1);
        MMX(2, 0); MMX(2, 1); MMX(3, 0); MMX(3, 1);
        __builtin_amdgcn_s_setprio(0);

        if (kt + 1 < nkt) {
            // need tile kt+1 landed; tiles beyond it still in flight:
            // kt <= nkt-4: 2 in flight -> vmcnt(8); kt == nkt-3: 1 -> vmcnt(4); kt == nkt-2: 0 -> vmcnt(0)
            if (kt + 4 <= nkt - 1)      asm volatile("s_waitcnt vmcnt(8)" ::: "memory");
            else if (kt + 3 <= nkt - 1) asm volatile("s_waitcnt vmcnt(4)" ::: "memory");
            else                        asm volatile("s_waitcnt vmcnt(0)" ::: "memory");
            asm volatile("s_barrier" ::: "memory");
        }
    }

    float sxv = fmaxf(__uint_as_float(hdr[0]), QEPS) / F8MAX;
    float swv = fmaxf(__uint_as_float(hdr[1]), QEPS) / F8MAX;
    float s = sxv * swv;

    // C/D 32x32: col = lane&31, row = (reg&3) + 8*(reg>>2) + 4*(lane>>5)
    #pragma unroll
    for (int m = 0; m < 4; m++) {
        int row0 = bm * 256 + wr * 128 + m * 32 + 4 * hl;
        #pragma unroll
        for (int n = 0; n < 2; n++) {
            int col = bn * 256 + wc * 64 + n * 32 + l31;
            float bv = bias[col];
            #pragma unroll
            for (int reg = 0; reg < 16; reg++) {
                int row = row0 + (reg & 3) + 8 * (reg >> 2);
                __builtin_nontemporal_store(acc[m][n][reg] * s + bv, &C[(size_t)row * N + col]);
            }
        }
    }
#undef ISSUE
#undef RD8
#undef MMX
}

extern "C" void kernel_launch(void* const* d_in, const int* in_sizes, int n_in,
                              void* d_out, int out_size, void* d_ws, size_t ws_size,
                              hipStream_t stream)
{
    const float* x    = (const float*)d_in[0];
    const float* w    = (const float*)d_in[1];
    const float* bias = (const float*)d_in[2];
    float* out = (float*)d_out;

    int N = in_sizes[2];                 // 1024
    int K = in_sizes[1] / N;             // 1024
    int M = in_sizes[0] / K;             // 65536
    int nx = in_sizes[0];
    int nw = in_sizes[1];
    int nkt = K / 64;                    // 16

    uint8_t* ws = (uint8_t*)d_ws;
    unsigned* hdr = (unsigned*)ws;                    // [0]=amax_x bits, [1]=amax_w bits
    float* px = (float*)(ws + 64);                    // 4096 partials (x)
    float* pw = (float*)(ws + 64 + 16384);            // 4096 partials (w)
    uint8_t* w8 = ws + 65536;
    uint8_t* x8 = ws + 65536 + (size_t)N * K;

    int nhx = (M / 128) * 2;             // 1024 half-panels of x
    int nhw = (N / 128) * 2;             // 16 half-panels of w

    amax_partial_xw<<<AXB, 256, 0, stream>>>(x, nx / 4, w, nw / 4, px, pw);
    quant_fused<<<nhw + nhx, 256, 0, stream>>>(x, w, x8, w8, px, pw, hdr, nhx, nkt, K);

    int nbm = M / 256, nbn = N / 256;    // 256 x 4 = 1024 blocks
    gemm_fp8_mx<<<nbm * nbn, 512, 0, stream>>>(x8, w8, out, bias, hdr, N, nkt, nbn);
}

// Round 12
// 204.137 us; speedup vs baseline: 1.1807x; 1.0662x over previous
//
#include <hip/hip_runtime.h>
#include <stdint.h>

#define F8MAX 448.0f
#define QEPS 1e-12f
#define SCL_ONE 0x7F7F7F7F   // E8M0 exponent 127 => 2^0 = 1.0 per byte
#define AXB 4096             // amax partial blocks

typedef float floatx16 __attribute__((ext_vector_type(16)));
typedef int   intx4    __attribute__((ext_vector_type(4)));
typedef int   intx8    __attribute__((ext_vector_type(8)));

// ---------------- pass 1: dual per-block amax partials (x and w in one kernel) ----------------
__global__ __launch_bounds__(256) void amax_partial_xw(
    const float* __restrict__ x, int nx4,
    const float* __restrict__ w, int nw4,
    float* __restrict__ px, float* __restrict__ pw)
{
    const float4* x4 = (const float4*)x;
    const float4* w4 = (const float4*)w;
    int tid = blockIdx.x * 256 + threadIdx.x;
    int stride = gridDim.x * 256;
    float mx = 0.f, mw = 0.f;
    for (int i = tid; i < nx4; i += stride) {
        float4 v = x4[i];
        mx = fmaxf(mx, fmaxf(fmaxf(fabsf(v.x), fabsf(v.y)), fmaxf(fabsf(v.z), fabsf(v.w))));
    }
    for (int i = tid; i < nw4; i += stride) {
        float4 v = w4[i];
        mw = fmaxf(mw, fmaxf(fmaxf(fabsf(v.x), fabsf(v.y)), fmaxf(fabsf(v.z), fabsf(v.w))));
    }
    #pragma unroll
    for (int off = 32; off > 0; off >>= 1) {
        mx = fmaxf(mx, __shfl_xor(mx, off, 64));
        mw = fmaxf(mw, __shfl_xor(mw, off, 64));
    }
    __shared__ float smx[4], smw[4];
    if ((threadIdx.x & 63) == 0) { smx[threadIdx.x >> 6] = mx; smw[threadIdx.x >> 6] = mw; }
    __syncthreads();
    if (threadIdx.x == 0) {
        px[blockIdx.x] = fmaxf(fmaxf(smx[0], smx[1]), fmaxf(smx[2], smx[3]));
        pw[blockIdx.x] = fmaxf(fmaxf(smw[0], smw[1]), fmaxf(smw[2], smw[3]));
    }
}

// ---------------- pass 2: quant, 32-row quarter-panels, 512 thr, 32KB LDS (100% occ) ----------
// Output layout identical: tile(p,kt) byte = h*4096 + pc*2048 + r*16 + (k&15), r in [0,128).
// Quarter q covers r in [q*32, q*32+32) -> 512B runs at chunk(kt,hpc) + q*512.
// LDS image: [16 kt][4 hpc][32 r][16B] = 32KB, XOR-swizzled on byte bits 4..6 with
// key = (lane>>2)&7 (phase A) == ((kt&1)<<2)|hpc (phase B) -- same derivation as before.
__global__ __launch_bounds__(512) void quant_fused(
    const float* __restrict__ x, const float* __restrict__ w,
    uint8_t* __restrict__ x8, uint8_t* __restrict__ w8,
    const float* __restrict__ px, const float* __restrict__ pw,
    unsigned* __restrict__ hdr, int nhx, int nkt, int K)
{
    __shared__ uint8_t lds[32768];

    int bid = blockIdx.x;
    bool isw = (bid < 32);                 // w: 32 quarter-panels (N=1024)
    const float* par = isw ? pw : px;

    // redundant reduce of the 4096-entry partial array (deterministic -> identical everywhere)
    float m = 0.f;
    for (int i = threadIdx.x; i < AXB; i += 512) m = fmaxf(m, par[i]);
    #pragma unroll
    for (int off = 32; off > 0; off >>= 1) m = fmaxf(m, __shfl_xor(m, off, 64));
    __shared__ float red[8];
    if ((threadIdx.x & 63) == 0) red[threadIdx.x >> 6] = m;
    __syncthreads();
    float amax = red[0];
    #pragma unroll
    for (int i = 1; i < 8; i++) amax = fmaxf(amax, red[i]);

    float scale = fmaxf(amax, QEPS) / F8MAX;   // exactly the reference's scale
    float rs = 1.0f / scale;                   // reciprocal-multiply

    if (threadIdx.x == 0) {
        if (bid == 0)  hdr[1] = __float_as_uint(amax);   // amax_w for gemm epilogue
        if (bid == 32) hdr[0] = __float_as_uint(amax);   // amax_x
    }

    int hp = isw ? bid : (nhx - 1 - (bid - 32));   // x back-to-front: L3 reuse after amax
    const float* src = isw ? w : x;
    uint8_t* dst8 = isw ? w8 : x8;
    int p = hp >> 2, q = hp & 3;                   // 128-row panel, quarter

    int wave = threadIdx.x >> 6, lane = threadIdx.x & 63;
    int K4 = K >> 2;

    // ---- phase A: 32 rows -> LDS (coalesced 1KB wave-reads) ----
    const float4* s4 = (const float4*)src + (size_t)hp * 32 * K4;
    uint32_t key = (lane >> 2) & 7;
    uint32_t lbase = ((uint32_t)(lane >> 4) * 2048) + (((lane >> 2) & 3) * 512) + ((lane & 3) * 4);
    #pragma unroll
    for (int rr = 0; rr < 4; rr++) {
        int r = rr * 8 + wave;                 // 0..31
        const float4* rowp = s4 + (size_t)r * K4;
        #pragma unroll
        for (int j = 0; j < 4; j++) {
            float4 f = rowp[j * 64 + lane];    // 1KB contiguous per wave-instr
            int wd = 0;
            wd = __builtin_amdgcn_cvt_pk_fp8_f32(f.x * rs, f.y * rs, wd, false);
            wd = __builtin_amdgcn_cvt_pk_fp8_f32(f.z * rs, f.w * rs, wd, true);
            uint32_t a = (uint32_t)j * 8192 + lbase + (uint32_t)r * 16;
            a ^= (key << 4);
            *(int*)(lds + a) = wd;
        }
    }
    __syncthreads();

    // ---- phase B: LDS -> global, 64 chunks x 512B, 512B contiguous per 32-lane group ----
    uint8_t* outb = dst8 + (size_t)(p * nkt) * 8192 + q * 512;
    int l32 = lane & 31, chi = lane >> 5;
    #pragma unroll
    for (int it = 0; it < 4; it++) {
        int c = it * 16 + wave * 2 + chi;      // chunk 0..63
        int kt = c >> 2, hpc = c & 3;
        uint32_t k2 = (uint32_t)(((kt & 1) << 2) | hpc);
        uint32_t a = (uint32_t)c * 512 + (((uint32_t)l32 * 16) ^ (k2 << 4));
        int4 v = *(const int4*)(lds + a);
        *(int4*)(outb + (size_t)kt * 8192 + hpc * 2048 + l32 * 16) = v;
    }
}

// ---------------- pass 3: MX-scaled fp8 GEMM, 256^2 tile, 4-buffer depth-3 pipeline ------------
// (byte-identical to round 11 — best known)
__global__ __launch_bounds__(512, 1) void gemm_fp8_mx(
    const uint8_t* __restrict__ A8, const uint8_t* __restrict__ B8,
    float* __restrict__ C, const float* __restrict__ bias,
    const unsigned* __restrict__ hdr, int N, int nkt, int nbn)
{
    __shared__ uint8_t lsA[4 * 16384];
    __shared__ uint8_t lsB[4 * 16384];

    int nwg = gridDim.x;
    int bid = blockIdx.x;
    if ((nwg & 7) == 0) {
        int chunk = nwg >> 3;
        bid = (blockIdx.x & 7) * chunk + (blockIdx.x >> 3);
    }
    int bm = bid / nbn, bn = bid - bm * nbn;

    int t = threadIdx.x;
    int wave = t >> 6, lane = t & 63;
    int wr = wave >> 2, wc = wave & 3;        // 2(M) x 4(N)
    int hl = lane >> 5, l31 = lane & 31;

    const uint8_t* gsrc0; const uint8_t* gsrc1; const uint8_t* gsrc2; const uint8_t* gsrc3;
    uint32_t ld0, ld1, ld2, ld3;
    bool isA = (wave < 4);
    {
        int c0 = wave * 4;
        #pragma unroll
        for (int p = 0; p < 4; p++) {
            int c = c0 + p;
            const uint8_t* g;
            uint32_t l;
            if (c < 16) {
                int h = c >> 3, sub = c & 7;
                g = A8 + (size_t)(bm * 2 + h) * nkt * 8192 + sub * 1024 + lane * 16;
                l = (uint32_t)c * 1024;
            } else {
                int cc = c - 16, h = cc >> 3, sub = cc & 7;
                g = B8 + (size_t)(bn * 2 + h) * nkt * 8192 + sub * 1024 + lane * 16;
                l = (uint32_t)cc * 1024;
            }
            if (p == 0) { gsrc0 = g; ld0 = l; }
            else if (p == 1) { gsrc1 = g; ld1 = l; }
            else if (p == 2) { gsrc2 = g; ld2 = l; }
            else { gsrc3 = g; ld3 = l; }
        }
    }
    uint8_t* lsbase = isA ? lsA : lsB;

#define ISSUE(GP, LO, KT2, B2)                                                   \
    __builtin_amdgcn_global_load_lds(                                            \
        (const __attribute__((address_space(1))) void*)((GP) + (size_t)(KT2) * 8192), \
        (__attribute__((address_space(3))) void*)(lsbase + (B2) * 16384 + (LO)), \
        16, 0, 0)

    const uint8_t* baseA = lsA + wr * 8192 + hl * 4096 + l31 * 16;
    const uint8_t* baseB = lsB + (wc >> 1) * 8192 + hl * 4096 + (wc & 1) * 1024 + l31 * 16;

    floatx16 acc[4][2];
    #pragma unroll
    for (int m = 0; m < 4; m++)
        #pragma unroll
        for (int n = 0; n < 2; n++)
            acc[m][n] = (floatx16)(0.0f);

#define RD8(BASE, OFF) __builtin_shufflevector(                         \
        *(const intx4*)((BASE) + (OFF)),                                \
        *(const intx4*)((BASE) + (OFF) + 2048), 0, 1, 2, 3, 4, 5, 6, 7)

#define MMX(m, n) acc[m][n] = __builtin_amdgcn_mfma_scale_f32_32x32x64_f8f6f4( \
        af[m], bf[n], acc[m][n], 0, 0, 0, SCL_ONE, 0, SCL_ONE)

    ISSUE(gsrc0, ld0, 0, 0); ISSUE(gsrc1, ld1, 0, 0); ISSUE(gsrc2, ld2, 0, 0); ISSUE(gsrc3, ld3, 0, 0);
    ISSUE(gsrc0, ld0, 1, 1); ISSUE(gsrc1, ld1, 1, 1); ISSUE(gsrc2, ld2, 1, 1); ISSUE(gsrc3, ld3, 1, 1);
    ISSUE(gsrc0, ld0, 2, 2); ISSUE(gsrc1, ld1, 2, 2); ISSUE(gsrc2, ld2, 2, 2); ISSUE(gsrc3, ld3, 2, 2);
    asm volatile("s_waitcnt vmcnt(8)" ::: "memory");   // tile 0 landed; 1,2 in flight
    asm volatile("s_barrier" ::: "memory");

    for (int kt = 0; kt < nkt; kt++) {
        int cur = kt & 3;
        int ib = (cur + 3) & 3;                         // (kt+3) % 4
        const uint8_t* cA = baseA + cur * 16384;
        const uint8_t* cB = baseB + cur * 16384;
        intx8 af[4], bf[2];

        if (kt + 3 < nkt) {
            ISSUE(gsrc0, ld0, kt + 3, ib); ISSUE(gsrc1, ld1, kt + 3, ib);
            ISSUE(gsrc2, ld2, kt + 3, ib); ISSUE(gsrc3, ld3, kt + 3, ib);
        }

        af[0] = RD8(cA, 0);    af[1] = RD8(cA, 512);
        bf[0] = RD8(cB, 0);    bf[1] = RD8(cB, 512);
        af[2] = RD8(cA, 1024); af[3] = RD8(cA, 1536);

        __builtin_amdgcn_s_setprio(1);
        MMX(0, 0); MMX(0, 1); MMX(1, 0); MMX(1, 1);
        MMX(2, 0); MMX(2, 1); MMX(3, 0); MMX(3, 1);
        __builtin_amdgcn_s_setprio(0);

        if (kt + 1 < nkt) {
            if (kt + 4 <= nkt - 1)      asm volatile("s_waitcnt vmcnt(8)" ::: "memory");
            else if (kt + 3 <= nkt - 1) asm volatile("s_waitcnt vmcnt(4)" ::: "memory");
            else                        asm volatile("s_waitcnt vmcnt(0)" ::: "memory");
            asm volatile("s_barrier" ::: "memory");
        }
    }

    float sxv = fmaxf(__uint_as_float(hdr[0]), QEPS) / F8MAX;
    float swv = fmaxf(__uint_as_float(hdr[1]), QEPS) / F8MAX;
    float s = sxv * swv;

    // C/D 32x32: col = lane&31, row = (reg&3) + 8*(reg>>2) + 4*(lane>>5)
    #pragma unroll
    for (int m = 0; m < 4; m++) {
        int row0 = bm * 256 + wr * 128 + m * 32 + 4 * hl;
        #pragma unroll
        for (int n = 0; n < 2; n++) {
            int col = bn * 256 + wc * 64 + n * 32 + l31;
            float bv = bias[col];
            #pragma unroll
            for (int reg = 0; reg < 16; reg++) {
                int row = row0 + (reg & 3) + 8 * (reg >> 2);
                __builtin_nontemporal_store(acc[m][n][reg] * s + bv, &C[(size_t)row * N + col]);
            }
        }
    }
#undef ISSUE
#undef RD8
#undef MMX
}

extern "C" void kernel_launch(void* const* d_in, const int* in_sizes, int n_in,
                              void* d_out, int out_size, void* d_ws, size_t ws_size,
                              hipStream_t stream)
{
    const float* x    = (const float*)d_in[0];
    const float* w    = (const float*)d_in[1];
    const float* bias = (const float*)d_in[2];
    float* out = (float*)d_out;

    int N = in_sizes[2];                 // 1024
    int K = in_sizes[1] / N;             // 1024
    int M = in_sizes[0] / K;             // 65536
    int nx = in_sizes[0];
    int nw = in_sizes[1];
    int nkt = K / 64;                    // 16

    uint8_t* ws = (uint8_t*)d_ws;
    unsigned* hdr = (unsigned*)ws;                    // [0]=amax_x bits, [1]=amax_w bits
    float* px = (float*)(ws + 64);                    // 4096 partials (x)
    float* pw = (float*)(ws + 64 + 16384);            // 4096 partials (w)
    uint8_t* w8 = ws + 65536;
    uint8_t* x8 = ws + 65536 + (size_t)N * K;

    int nhx = M / 32;                    // 2048 quarter-panels of x
    int nhw = N / 32;                    // 32 quarter-panels of w

    amax_partial_xw<<<AXB, 256, 0, stream>>>(x, nx / 4, w, nw / 4, px, pw);
    quant_fused<<<nhw + nhx, 512, 0, stream>>>(x, w, x8, w8, px, pw, hdr, nhx, nkt, K);

    int nbm = M / 256, nbn = N / 256;    // 256 x 4 = 1024 blocks
    gemm_fp8_mx<<<nbm * nbn, 512, 0, stream>>>(x8, w8, out, bias, hdr, N, nkt, nbn);
}